// Round 1
// 584.331 us; speedup vs baseline: 1.0335x; 1.0335x over previous
//
#include <hip/hip_runtime.h>
#include <hip/hip_bf16.h>
#include <hip/hip_fp16.h>

#define NB 256      // batch
#define NT 1024     // time
#define ND 64       // input dim
#define NH 128      // hidden dim

typedef __fp16 half8 __attribute__((ext_vector_type(8)));
typedef __fp16 half4v __attribute__((ext_vector_type(4)));
typedef __fp16 half2v __attribute__((ext_vector_type(2)));
typedef float float4v __attribute__((ext_vector_type(4)));

static __device__ __forceinline__ float fast_tanh(float v) {
    float e = __expf(2.0f * v);
    return 1.0f - 2.0f * __builtin_amdgcn_rcpf(e + 1.0f);
}

static __device__ __forceinline__ float fdot2f(half2v a, half2v b, float c) {
#if __has_builtin(__builtin_amdgcn_fdot2)
    return __builtin_amdgcn_fdot2(a, b, c, false);
#else
    return c + (float)a.x * (float)b.x + (float)a.y * (float)b.y;
#endif
}

// lgkm-only barrier: does NOT drain vmcnt (global stores / x prefetch keep flying)
static __device__ __forceinline__ void fast_barrier() {
    asm volatile("s_waitcnt lgkmcnt(0)\n\ts_barrier" ::: "memory");
}

static __device__ __forceinline__ float dpp_xor1_add(float x) {
#if __has_builtin(__builtin_amdgcn_mov_dpp)
    int o = __builtin_amdgcn_mov_dpp(__builtin_bit_cast(int, x), 0xB1, 0xF, 0xF, true);
    return x + __builtin_bit_cast(float, o);
#else
    return x + __shfl_xor(x, 1);
#endif
}

// Fully fused: per-chunk input projections (idle MFMA pipe) + sequential recurrence.
// grid 256 (block = batch) x 256 threads. Recurrence thread: j = tid>>1, kh = tid&1.
__global__ __launch_bounds__(256) void fused_rnn_kernel(
        const float* __restrict__ x,
        const float* __restrict__ WxK, const float* __restrict__ bxK,
        const float* __restrict__ Wxz, const float* __restrict__ bxz,
        const float* __restrict__ Whk, const float* __restrict__ bhk,
        float* __restrict__ out) {
    __shared__ __align__(16) __fp16 wsm[2][128][72];    // 36 KB: W_xK / W_xz fp16, row-major [h][d]
    __shared__ __align__(16) __fp16 xsm[16][72];        // 2.25 KB: one x chunk (16 t x 64 d) fp16
    __shared__ __align__(16) __fp16 hbuf[2][128];       // h as fp16, dbuf per step
    __shared__ __align__(16) __fp16 gbuf[2][16][132];   // gxK chunk dbuf (pad 132: conflict-free epilogue)
    __shared__ __align__(16) __fp16 zbuf[2][16][132];   // z   chunk dbuf

    const int tid = threadIdx.x;
    const int b = blockIdx.x;
    const int wid = tid >> 6, lane = tid & 63;
    const int l16 = lane & 15, kg = lane >> 4;
    const int j = tid >> 1, kh = tid & 1;

    // ---- stage W_xK / W_xz into LDS as fp16, once ----
    #pragma unroll
    for (int mat = 0; mat < 2; ++mat) {
        const float* Wsrc = mat ? Wxz : WxK;
        const float4v* ws4 = (const float4v*)(Wsrc + (size_t)(tid >> 1) * 64 + (tid & 1) * 32);
        #pragma unroll
        for (int i = 0; i < 4; ++i) {
            float4v a = ws4[2 * i], c = ws4[2 * i + 1];
            half8 hv = {(__fp16)a.x, (__fp16)a.y, (__fp16)a.z, (__fp16)a.w,
                        (__fp16)c.x, (__fp16)c.y, (__fp16)c.z, (__fp16)c.w};
            *(half8*)&wsm[mat][tid >> 1][(tid & 1) * 32 + i * 8] = hv;
        }
    }

    // ---- W_hK row j, k-half kh, packed fp16 in 32 VGPRs ----
    half2v w[32];
    {
        const float4v* wsrc = (const float4v*)(Whk + (size_t)j * NH + kh * 64);
        #pragma unroll
        for (int i = 0; i < 16; ++i) {
            float4v wv = wsrc[i];
            w[2 * i]     = __builtin_amdgcn_cvt_pkrtz(wv.x, wv.y);
            w[2 * i + 1] = __builtin_amdgcn_cvt_pkrtz(wv.z, wv.w);
        }
    }
    const float bj = bhk[j];

    // per-thread projection-epilogue columns + biases (C layout: col = nt*16+l16, row = kg*4+r)
    const int hc0 = (2 * wid + 0) * 16 + l16;
    const int hc1 = (2 * wid + 1) * 16 + l16;
    const float bK0 = bxK[hc0], bK1 = bxK[hc1];
    const float bz0 = bxz[hc0], bz1 = bxz[hc1];

    const float4v* xsrc = (const float4v*)(x + (size_t)b * NT * ND);

    // 16x64x128 x2 GEMM for one staged x chunk; 8 MFMAs per wave (2 nt-tiles x 2 mats x 2 k-steps)
    auto proj_mfma = [&](float4v (&pacc)[2][2]) {
        #pragma unroll
        for (int n2 = 0; n2 < 2; ++n2)
            #pragma unroll
            for (int mat = 0; mat < 2; ++mat)
                pacc[n2][mat] = (float4v){0.f, 0.f, 0.f, 0.f};
        #pragma unroll
        for (int ks = 0; ks < 2; ++ks) {
            half8 af = *(const half8*)&xsm[l16][ks * 32 + kg * 8];
            #pragma unroll
            for (int n2 = 0; n2 < 2; ++n2) {
                const int nt = 2 * wid + n2;
                #pragma unroll
                for (int mat = 0; mat < 2; ++mat) {
                    half8 bf = *(const half8*)&wsm[mat][nt * 16 + l16][ks * 32 + kg * 8];
                    pacc[n2][mat] =
                        __builtin_amdgcn_mfma_f32_16x16x32_f16(af, bf, pacc[n2][mat], 0, 0, 0);
                }
            }
        }
    };
    auto proj_epilogue = [&](float4v (&pacc)[2][2], int dst) {
        #pragma unroll
        for (int n2 = 0; n2 < 2; ++n2) {
            const int col = (2 * wid + n2) * 16 + l16;
            const float bK = n2 ? bK1 : bK0;
            const float bz = n2 ? bz1 : bz0;
            #pragma unroll
            for (int r = 0; r < 4; ++r) {
                const int row = kg * 4 + r;
                gbuf[dst][row][col] = (__fp16)(pacc[n2][0][r] + bK);
                zbuf[dst][row][col] = (__fp16)fast_tanh(pacc[n2][1][r] + bz);
            }
        }
    };

    // ---- prologue: stage x chunk 0, project into buf 0 ----
    {
        float4v xg = xsrc[tid];                       // 16x64 f32 tile, 1 float4/thread
        if (tid < 128) hbuf[0][tid] = (__fp16)0.0f;   // h0 = 0
        __syncthreads();                              // wsm ready
        half4v hx = {(__fp16)xg.x, (__fp16)xg.y, (__fp16)xg.z, (__fp16)xg.w};
        *(half4v*)&xsm[tid >> 4][(tid & 15) * 4] = hx;
        __syncthreads();                              // xsm ready
        float4v pacc[2][2];
        proj_mfma(pacc);
        proj_epilogue(pacc, 0);
        __syncthreads();                              // gbuf/zbuf[0] ready
    }

    float hn = 0.0f;
    float oreg[16];
    const size_t obase = (size_t)kh * ((size_t)NB * NT * NH)
                       + (size_t)b * NT * NH + j;

    for (int c = 0; c < 64; ++c) {
        const int cb = c & 1;
        const bool more = (c + 1 < 64);

        // issue global prefetch of next x chunk (regs; consumed at s==2)
        float4v xgn;
        if (more) xgn = xsrc[(c + 1) * 256 + tid];

        // per-chunk gx/z for this thread's j -> registers (off critical path)
        float gxv[16], zvv[16];
        #pragma unroll
        for (int s = 0; s < 16; ++s) {
            gxv[s] = (float)gbuf[cb][s][j] + bj;
            zvv[s] = (float)zbuf[cb][s][j];
        }

        float4v pacc[2][2];   // projection accumulators, live s4 -> s6

        #pragma unroll
        for (int s = 0; s < 16; ++s) {
            const int t = c * 16 + s;
            const half8* hs = (const half8*)&hbuf[t & 1][kh * 64];
            float a0 = 0.f, a1 = 0.f, a2 = 0.f, a3 = 0.f;
            #pragma unroll
            for (int i = 0; i < 8; ++i) {
                half8 hv = hs[i];
                a0 = fdot2f(w[4 * i + 0], __builtin_shufflevector(hv, hv, 0, 1), a0);
                a1 = fdot2f(w[4 * i + 1], __builtin_shufflevector(hv, hv, 2, 3), a1);
                a2 = fdot2f(w[4 * i + 2], __builtin_shufflevector(hv, hv, 4, 5), a2);
                a3 = fdot2f(w[4 * i + 3], __builtin_shufflevector(hv, hv, 6, 7), a3);
            }
            const float acc = (a0 + a1) + (a2 + a3);
            const float gh = dpp_xor1_add(acc);          // pair k-halves via DPP

            const float d = zvv[s] - hn;                 // off-chain vs gh
            const float pre = gh + gxv[s];
            const float Kg = __builtin_amdgcn_rcpf(1.0f + __expf(-pre));
            const float v = __builtin_fmaf(Kg, d, hn);
            hn = fast_tanh(v);
            oreg[s] = hn;

            if (kh == 0) hbuf[(t + 1) & 1][j] = (__fp16)hn;

            // ---- grafted next-chunk projection, hidden in the idle pipes ----
            if (s == 2 && more) {                        // stage x(c+1): regs -> LDS fp16
                half4v hx = {(__fp16)xgn.x, (__fp16)xgn.y, (__fp16)xgn.z, (__fp16)xgn.w};
                *(half4v*)&xsm[tid >> 4][(tid & 15) * 4] = hx;
            }
            if (s == 4 && more) proj_mfma(pacc);         // MFMA pipe is otherwise idle
            if (s == 6 && more) proj_epilogue(pacc, cb ^ 1);

            fast_barrier();                              // lgkm-only, no vmcnt drain
        }

        // flush 16 outputs (coalesced per t); drains in background
        #pragma unroll
        for (int s = 0; s < 16; ++s)
            out[obase + (size_t)(c * 16 + s) * NH] = oreg[s];
    }
}

extern "C" void kernel_launch(void* const* d_in, const int* in_sizes, int n_in,
                              void* d_out, int out_size, void* d_ws, size_t ws_size,
                              hipStream_t stream) {
    (void)in_sizes; (void)n_in; (void)d_ws; (void)ws_size; (void)out_size;
    const float* x   = (const float*)d_in[0];
    const float* WxK = (const float*)d_in[1];
    const float* bxK = (const float*)d_in[2];
    const float* Wxz = (const float*)d_in[3];
    const float* bxz = (const float*)d_in[4];
    const float* Whk = (const float*)d_in[5];
    const float* bhk = (const float*)d_in[6];
    float* out = (float*)d_out;

    fused_rnn_kernel<<<256, 256, 0, stream>>>(x, WxK, bxK, Wxz, bxz, Whk, bhk, out);
}